// Round 2
// baseline (415.626 us; speedup 1.0000x reference)
//
#include <hip/hip_runtime.h>

// CausalInterventionAttention: B=2, S=2048, D=1024, H=16, HD=64
// Pipeline (all launches on `stream`):
//   1. cvt_x: x fp32 -> bf16
//   2. cvt_w x4: W fp32 [k][n] -> bf16 Wt [n][k] (transposed for contiguous B-frags)
//   3. gemm<0> x2: q,k = x@W+b  -> bf16 [b][h][s][d]
//   4. gemm<1>: v -> bf16 Vt [b][h][d][s] (pre-transposed for PV B-frags)
//   5. attn: flash attention, bf16 MFMA, fp32 online softmax, mask-scaled scores
//   6. gemm<2>: out = att@Wo + bo -> fp32 d_out

typedef __attribute__((ext_vector_type(8))) short bf16x8;
typedef __attribute__((ext_vector_type(4))) float f32x4;

__device__ __forceinline__ unsigned short f2b(float f) {
  union { float f; unsigned u; } x; x.f = f;
  unsigned r = x.u + 0x7FFFu + ((x.u >> 16) & 1u);  // RNE
  return (unsigned short)(r >> 16);
}

__device__ __forceinline__ void gl_lds16(const unsigned short* g, unsigned short* l) {
  __builtin_amdgcn_global_load_lds(
      (const __attribute__((address_space(1))) unsigned int*)g,
      (__attribute__((address_space(3))) unsigned int*)l, 16, 0, 0);
}

// ---------------- conversion kernels ----------------

__global__ __launch_bounds__(256) void cvt_x_kernel(const float* __restrict__ x,
                                                    unsigned short* __restrict__ xb, int n4) {
  int i = blockIdx.x * 256 + threadIdx.x;
  if (i >= n4) return;
  float4 v = ((const float4*)x)[i];
  ushort4 o;
  o.x = f2b(v.x); o.y = f2b(v.y); o.z = f2b(v.z); o.w = f2b(v.w);
  ((ushort4*)xb)[i] = o;
}

// W [1024 k][1024 n] fp32 -> Wt [1024 n][1024 k] bf16
__global__ void cvt_w_kernel(const float* __restrict__ W, unsigned short* __restrict__ Wt) {
  __shared__ float t[32][33];
  const int k0 = blockIdx.x * 32, n0 = blockIdx.y * 32;
  const int tx = threadIdx.x, ty = threadIdx.y;  // block (32,8)
  #pragma unroll
  for (int i = 0; i < 32; i += 8)
    t[ty + i][tx] = W[(size_t)(k0 + ty + i) * 1024 + n0 + tx];
  __syncthreads();
  #pragma unroll
  for (int i = 0; i < 32; i += 8)
    Wt[(size_t)(n0 + ty + i) * 1024 + k0 + tx] = f2b(t[tx][ty + i]);
}

// ---------------- GEMM: C(4096x1024) = A(4096x1024) @ Bt(1024n x 1024k)^T ----------------
// MODE 0: dst bf16 q/k layout [b][h][s][d]; MODE 1: dst bf16 Vt layout [b][h][d][s];
// MODE 2: dst fp32 row-major [4096][1024]
template <int MODE>
__global__ __launch_bounds__(256) void gemm_bt(const unsigned short* __restrict__ A,
                                               const unsigned short* __restrict__ Bt,
                                               const float* __restrict__ bias,
                                               void* __restrict__ dst) {
  __shared__ unsigned short As[2][4096];  // [128][32]
  __shared__ unsigned short Bs[2][2048];  // [64][32]
  const int tid = threadIdx.x;
  const int w = tid >> 6, lane = tid & 63;
  const int li = lane & 15, g = lane >> 4;
  const int wm = w >> 1, wn = w & 1;
  const int m0 = blockIdx.x * 128, n0 = blockIdx.y * 64;

  const int srow = tid >> 2;            // staging row (128 for A via 2 loads, 64 for B)
  const int scol = (tid & 3) * 8;
  const unsigned short* gA0 = A + (size_t)(m0 + srow) * 1024 + scol;
  const unsigned short* gA1 = gA0 + (size_t)64 * 1024;
  const unsigned short* gB0 = Bt + (size_t)(n0 + srow) * 1024 + scol;

  f32x4 acc[4][2];
  #pragma unroll
  for (int i = 0; i < 4; i++)
    #pragma unroll
    for (int j = 0; j < 2; j++) acc[i][j] = (f32x4){0.f, 0.f, 0.f, 0.f};

#define STAGE(buf, kt)                                  \
  {                                                     \
    const int ko = (kt) * 32;                           \
    gl_lds16(gA0 + ko, &As[buf][w * 512]);              \
    gl_lds16(gA1 + ko, &As[buf][2048 + w * 512]);       \
    gl_lds16(gB0 + ko, &Bs[buf][w * 512]);              \
  }

  STAGE(0, 0)
  #pragma unroll 2
  for (int kt = 0; kt < 32; kt++) {
    if (kt + 1 < 32) STAGE((kt + 1) & 1, kt + 1)
    __syncthreads();
    const int buf = kt & 1;
    bf16x8 af[4], bfr[2];
    #pragma unroll
    for (int mt = 0; mt < 4; mt++)
      af[mt] = *(const bf16x8*)&As[buf][(wm * 64 + mt * 16 + li) * 32 + g * 8];
    #pragma unroll
    for (int nt = 0; nt < 2; nt++)
      bfr[nt] = *(const bf16x8*)&Bs[buf][(wn * 32 + nt * 16 + li) * 32 + g * 8];
    #pragma unroll
    for (int mt = 0; mt < 4; mt++)
      #pragma unroll
      for (int nt = 0; nt < 2; nt++)
        acc[mt][nt] = __builtin_amdgcn_mfma_f32_16x16x32_bf16(af[mt], bfr[nt], acc[mt][nt], 0, 0, 0);
    __syncthreads();
  }
#undef STAGE

  #pragma unroll
  for (int nt = 0; nt < 2; nt++) {
    const int gc = n0 + wn * 32 + nt * 16 + li;
    const float bv = bias[gc];
    #pragma unroll
    for (int mt = 0; mt < 4; mt++) {
      #pragma unroll
      for (int r = 0; r < 4; r++) {
        const int gr = m0 + wm * 64 + mt * 16 + g * 4 + r;
        const float v = acc[mt][nt][r] + bv;
        if (MODE == 0) {
          const int bb = gr >> 11, s = gr & 2047, h = gc >> 6, d = gc & 63;
          ((unsigned short*)dst)[((size_t)(bb * 16 + h) * 2048 + s) * 64 + d] = f2b(v);
        } else if (MODE == 1) {
          const int bb = gr >> 11, s = gr & 2047, h = gc >> 6, d = gc & 63;
          ((unsigned short*)dst)[((size_t)(bb * 16 + h) * 64 + d) * 2048 + s] = f2b(v);
        } else {
          ((float*)dst)[(size_t)gr * 1024 + gc] = v;
        }
      }
    }
  }
}

// ---------------- flash attention ----------------
// grid (S/64, B*H), block 256 (4 waves x 16 q-rows). K/V read from global (L2-resident).
__global__ __launch_bounds__(256) void attn_kernel(
    const unsigned short* __restrict__ qb, const unsigned short* __restrict__ kb,
    const unsigned short* __restrict__ vtb, const int* __restrict__ cause,
    const int* __restrict__ effect, const float* __restrict__ strength,
    unsigned short* __restrict__ attb) {
  const int tid = threadIdx.x;
  const int w = tid >> 6, lane = tid & 63;
  const int g = lane >> 4, li = lane & 15;
  const int bh = blockIdx.y, b = bh >> 4, h = bh & 15;
  const int q0 = blockIdx.x * 64 + w * 16;

  // Q fragment (16 rows x 64 d) held in registers
  const unsigned short* qrow = qb + ((size_t)bh * 2048 + q0 + li) * 64 + g * 8;
  const bf16x8 qa0 = *(const bf16x8*)(qrow);
  const bf16x8 qa1 = *(const bf16x8*)(qrow + 32);

  int cm[4];
  #pragma unroll
  for (int r = 0; r < 4; r++) cm[r] = cause[b * 2048 + q0 + g * 4 + r];

  const float fmask = 1.0f - 0.5f * strength[0];

  float m[4], l[4];
  f32x4 acc[4];
  #pragma unroll
  for (int r = 0; r < 4; r++) { m[r] = -1e30f; l[r] = 0.f; }
  #pragma unroll
  for (int c = 0; c < 4; c++) acc[c] = (f32x4){0.f, 0.f, 0.f, 0.f};

  __shared__ unsigned short P[4][16][32];  // per-wave P tile round-trip

  const unsigned short* kbp = kb + (size_t)bh * 2048 * 64;
  const unsigned short* vbp = vtb + (size_t)bh * 64 * 2048;
  const int* eff = effect + b * 2048;

  for (int kt = 0; kt < 64; kt++) {
    const int kk = kt * 32;
    // QK^T for 16q x 32k
    f32x4 s0 = (f32x4){0.f, 0.f, 0.f, 0.f}, s1 = (f32x4){0.f, 0.f, 0.f, 0.f};
    {
      const unsigned short* kr = kbp + (size_t)(kk + li) * 64 + g * 8;
      const bf16x8 kf0 = *(const bf16x8*)(kr);
      const bf16x8 kf1 = *(const bf16x8*)(kr + 32);
      s0 = __builtin_amdgcn_mfma_f32_16x16x32_bf16(qa0, kf0, s0, 0, 0, 0);
      s0 = __builtin_amdgcn_mfma_f32_16x16x32_bf16(qa1, kf1, s0, 0, 0, 0);
      const unsigned short* kr2 = kr + 16 * 64;
      const bf16x8 kf2 = *(const bf16x8*)(kr2);
      const bf16x8 kf3 = *(const bf16x8*)(kr2 + 32);
      s1 = __builtin_amdgcn_mfma_f32_16x16x32_bf16(qa0, kf2, s1, 0, 0, 0);
      s1 = __builtin_amdgcn_mfma_f32_16x16x32_bf16(qa1, kf3, s1, 0, 0, 0);
    }
    const int em0 = eff[kk + li], em1 = eff[kk + 16 + li];
    float sv[2][4];
    #pragma unroll
    for (int r = 0; r < 4; r++) {
      sv[0][r] = s0[r] * ((cm[r] & em0) ? 0.125f * fmask : 0.125f);
      sv[1][r] = s1[r] * ((cm[r] & em1) ? 0.125f * fmask : 0.125f);
    }
    // online softmax (rows live in 16-lane groups)
    float pm[4];
    #pragma unroll
    for (int r = 0; r < 4; r++) pm[r] = fmaxf(sv[0][r], sv[1][r]);
    #pragma unroll
    for (int off = 1; off < 16; off <<= 1)
      #pragma unroll
      for (int r = 0; r < 4; r++) pm[r] = fmaxf(pm[r], __shfl_xor(pm[r], off, 16));
    float sc[4], ps[4];
    #pragma unroll
    for (int r = 0; r < 4; r++) {
      const float mn = fmaxf(m[r], pm[r]);
      sc[r] = __expf(m[r] - mn);
      m[r] = mn;
      sv[0][r] = __expf(sv[0][r] - mn);
      sv[1][r] = __expf(sv[1][r] - mn);
      ps[r] = sv[0][r] + sv[1][r];
    }
    #pragma unroll
    for (int off = 1; off < 16; off <<= 1)
      #pragma unroll
      for (int r = 0; r < 4; r++) ps[r] += __shfl_xor(ps[r], off, 16);
    #pragma unroll
    for (int r = 0; r < 4; r++) l[r] = l[r] * sc[r] + ps[r];
    #pragma unroll
    for (int c = 0; c < 4; c++)
      #pragma unroll
      for (int r = 0; r < 4; r++) acc[c][r] *= sc[r];
    // P -> LDS (C-layout) -> A-frag (in-order LDS per wave, no barrier: per-wave region)
    #pragma unroll
    for (int r = 0; r < 4; r++) {
      P[w][g * 4 + r][li] = f2b(sv[0][r]);
      P[w][g * 4 + r][16 + li] = f2b(sv[1][r]);
    }
    const bf16x8 pa = *(const bf16x8*)&P[w][li][g * 8];
    // PV: out(16x64) += P(16x32) @ V(32x64), B-frags contiguous from Vt
    #pragma unroll
    for (int c = 0; c < 4; c++) {
      const unsigned short* vr = vbp + (size_t)(c * 16 + li) * 2048 + kk + g * 8;
      const bf16x8 vf = *(const bf16x8*)(vr);
      acc[c] = __builtin_amdgcn_mfma_f32_16x16x32_bf16(pa, vf, acc[c], 0, 0, 0);
    }
  }
  #pragma unroll
  for (int r = 0; r < 4; r++) l[r] = 1.0f / l[r];
  #pragma unroll
  for (int c = 0; c < 4; c++)
    #pragma unroll
    for (int r = 0; r < 4; r++) {
      const int row = q0 + g * 4 + r;
      attb[(size_t)(b * 2048 + row) * 1024 + h * 64 + c * 16 + li] = f2b(acc[c][r] * l[r]);
    }
}

// ---------------- launch ----------------

extern "C" void kernel_launch(void* const* d_in, const int* in_sizes, int n_in,
                              void* d_out, int out_size, void* d_ws, size_t ws_size,
                              hipStream_t stream) {
  (void)in_sizes; (void)n_in; (void)out_size; (void)ws_size;
  const float* x = (const float*)d_in[0];
  const int* cause = (const int*)d_in[1];
  const int* effect = (const int*)d_in[2];
  const float* strength = (const float*)d_in[3];
  const float* Wq = (const float*)d_in[4];
  const float* bq = (const float*)d_in[5];
  const float* Wk = (const float*)d_in[6];
  const float* bk = (const float*)d_in[7];
  const float* Wv = (const float*)d_in[8];
  const float* bv = (const float*)d_in[9];
  const float* Wo = (const float*)d_in[10];
  const float* bo = (const float*)d_in[11];
  float* out = (float*)d_out;

  char* ws = (char*)d_ws;
  unsigned short* xb  = (unsigned short*)(ws);                     // 8 MB
  unsigned short* wqt = (unsigned short*)(ws + (8u << 20));        // 2 MB each
  unsigned short* wkt = (unsigned short*)(ws + (10u << 20));
  unsigned short* wvt = (unsigned short*)(ws + (12u << 20));
  unsigned short* wot = (unsigned short*)(ws + (14u << 20));
  unsigned short* qbf = (unsigned short*)(ws + (16u << 20));       // 8 MB
  unsigned short* kbf = (unsigned short*)(ws + (24u << 20));       // 8 MB
  unsigned short* vtb = (unsigned short*)(ws + (32u << 20));       // 8 MB
  unsigned short* attb = xb;  // reuse x's bf16 buffer after projections

  cvt_x_kernel<<<4096, 256, 0, stream>>>(x, xb, 1048576);
  dim3 tg(32, 32), tb(32, 8);
  cvt_w_kernel<<<tg, tb, 0, stream>>>(Wq, wqt);
  cvt_w_kernel<<<tg, tb, 0, stream>>>(Wk, wkt);
  cvt_w_kernel<<<tg, tb, 0, stream>>>(Wv, wvt);
  cvt_w_kernel<<<tg, tb, 0, stream>>>(Wo, wot);

  dim3 gg(32, 16);
  gemm_bt<0><<<gg, 256, 0, stream>>>(xb, wqt, bq, (void*)qbf);
  gemm_bt<0><<<gg, 256, 0, stream>>>(xb, wkt, bk, (void*)kbf);
  gemm_bt<1><<<gg, 256, 0, stream>>>(xb, wvt, bv, (void*)vtb);
  attn_kernel<<<dim3(32, 32), 256, 0, stream>>>(qbf, kbf, vtb, cause, effect, strength, attb);
  gemm_bt<2><<<gg, 256, 0, stream>>>(attb, wot, bo, (void*)out);
}

// Round 4
// 277.813 us; speedup vs baseline: 1.4961x; 1.4961x over previous
//
#include <hip/hip_runtime.h>

// CausalInterventionAttention: B=2, S=2048, D=1024, H=16, HD=64
// Round 3: same as round 2 (fused QKV GEMM m97-structure, attn with swizzled
// LDS K/V staging, defer-rescale, XCD-bijective swizzle) + call-site fix.

typedef __attribute__((ext_vector_type(8))) short bf16x8;
typedef __attribute__((ext_vector_type(4))) float f32x4;

__device__ __forceinline__ unsigned short f2b(float f) {
  union { float f; unsigned u; } x; x.f = f;
  unsigned r = x.u + 0x7FFFu + ((x.u >> 16) & 1u);  // RNE
  return (unsigned short)(r >> 16);
}

__device__ __forceinline__ void gl_lds16(const unsigned short* g, unsigned short* l) {
  __builtin_amdgcn_global_load_lds(
      (const __attribute__((address_space(1))) unsigned int*)g,
      (__attribute__((address_space(3))) unsigned int*)l, 16, 0, 0);
}

// ---------------- conversion kernels ----------------

__global__ __launch_bounds__(256) void cvt_x_kernel(const float* __restrict__ x,
                                                    unsigned short* __restrict__ xb, int n4) {
  int i = blockIdx.x * 256 + threadIdx.x;
  if (i >= n4) return;
  float4 v = ((const float4*)x)[i];
  ushort4 o;
  o.x = f2b(v.x); o.y = f2b(v.y); o.z = f2b(v.z); o.w = f2b(v.w);
  ((ushort4*)xb)[i] = o;
}

// W [1024 k][1024 n] fp32 -> Wt [1024 n][1024 k] bf16
__global__ void cvt_w_kernel(const float* __restrict__ W, unsigned short* __restrict__ Wt) {
  __shared__ float t[32][33];
  const int k0 = blockIdx.x * 32, n0 = blockIdx.y * 32;
  const int tx = threadIdx.x, ty = threadIdx.y;  // block (32,8)
  #pragma unroll
  for (int i = 0; i < 32; i += 8)
    t[ty + i][tx] = W[(size_t)(k0 + ty + i) * 1024 + n0 + tx];
  __syncthreads();
  #pragma unroll
  for (int i = 0; i < 32; i += 8)
    Wt[(size_t)(n0 + ty + i) * 1024 + k0 + tx] = f2b(t[tx][ty + i]);
}

// ---------------- GEMM 128x128 (m97 structure) ----------------
// MODE 0: fused QKV (Bt = [3072 n][1024 k]); n-range selects dst q/k/vt + bias.
// MODE 1: out-proj, f32 row-major dst.
template <int MODE>
__global__ __launch_bounds__(256) void gemm128(
    const unsigned short* __restrict__ A, const unsigned short* __restrict__ Bt,
    const float* __restrict__ b0, const float* __restrict__ b1, const float* __restrict__ b2,
    unsigned short* __restrict__ dq, unsigned short* __restrict__ dk,
    unsigned short* __restrict__ dv, float* __restrict__ dout) {
  __shared__ unsigned short As[2][4096];  // [128][32]
  __shared__ unsigned short Bs[2][4096];  // [128][32]
  const int tid = threadIdx.x;
  const int w = tid >> 6, lane = tid & 63;
  const int li = lane & 15, g = lane >> 4;
  const int wm = w >> 1, wn = w & 1;
  const int m0 = blockIdx.x * 128, n0 = blockIdx.y * 128;

  const int seg0 = w * 2, seg1 = w * 2 + 1;
  const int srow0 = seg0 * 16 + (lane >> 2), srow1 = seg1 * 16 + (lane >> 2);
  const int scol = (lane & 3) * 8;
  const unsigned short* gA0 = A + (size_t)(m0 + srow0) * 1024 + scol;
  const unsigned short* gA1 = A + (size_t)(m0 + srow1) * 1024 + scol;
  const unsigned short* gB0 = Bt + (size_t)(n0 + srow0) * 1024 + scol;
  const unsigned short* gB1 = Bt + (size_t)(n0 + srow1) * 1024 + scol;

  f32x4 acc[4][4];
  #pragma unroll
  for (int i = 0; i < 4; i++)
    #pragma unroll
    for (int j = 0; j < 4; j++) acc[i][j] = (f32x4){0.f, 0.f, 0.f, 0.f};

#define GSTAGE(bufi, kt)                                 \
  {                                                      \
    const int ko = (kt) * 32;                            \
    gl_lds16(gA0 + ko, &As[bufi][seg0 * 512]);           \
    gl_lds16(gA1 + ko, &As[bufi][seg1 * 512]);           \
    gl_lds16(gB0 + ko, &Bs[bufi][seg0 * 512]);           \
    gl_lds16(gB1 + ko, &Bs[bufi][seg1 * 512]);           \
  }

  GSTAGE(0, 0)
  int buf = 0;
  for (int kt = 0; kt < 32; kt++) {
    __syncthreads();                    // stage(kt) landed; buf^1 free to overwrite
    if (kt + 1 < 32) GSTAGE(buf ^ 1, kt + 1)
    bf16x8 af[4], bfr[4];
    #pragma unroll
    for (int mt = 0; mt < 4; mt++)
      af[mt] = *(const bf16x8*)&As[buf][(wm * 64 + mt * 16 + li) * 32 + g * 8];
    #pragma unroll
    for (int nt = 0; nt < 4; nt++)
      bfr[nt] = *(const bf16x8*)&Bs[buf][(wn * 64 + nt * 16 + li) * 32 + g * 8];
    #pragma unroll
    for (int mt = 0; mt < 4; mt++)
      #pragma unroll
      for (int nt = 0; nt < 4; nt++)
        acc[mt][nt] = __builtin_amdgcn_mfma_f32_16x16x32_bf16(af[mt], bfr[nt], acc[mt][nt], 0, 0, 0);
    buf ^= 1;
  }
#undef GSTAGE

  if (MODE == 0) {
    const int sel = n0 >> 10;  // 128-tiles never straddle the 1024 boundaries
    const float* bp = sel == 0 ? b0 : (sel == 1 ? b1 : b2);
    unsigned short* dst = sel == 0 ? dq : (sel == 1 ? dk : dv);
    #pragma unroll
    for (int nt = 0; nt < 4; nt++) {
      const int gc = n0 + wn * 64 + nt * 16 + li;
      const int c = gc & 1023, h = c >> 6, d = c & 63;
      const float bv = bp[c];
      #pragma unroll
      for (int mt = 0; mt < 4; mt++)
        #pragma unroll
        for (int r = 0; r < 4; r++) {
          const int gr = m0 + wm * 64 + mt * 16 + g * 4 + r;
          const int bb = gr >> 11, s = gr & 2047;
          const float v = acc[mt][nt][r] + bv;
          if (sel < 2)
            dst[((size_t)(bb * 16 + h) * 2048 + s) * 64 + d] = f2b(v);
          else
            dst[((size_t)(bb * 16 + h) * 64 + d) * 2048 + s] = f2b(v);
        }
    }
  } else {
    #pragma unroll
    for (int nt = 0; nt < 4; nt++) {
      const int gc = n0 + wn * 64 + nt * 16 + li;
      const float bv = b0[gc];
      #pragma unroll
      for (int mt = 0; mt < 4; mt++)
        #pragma unroll
        for (int r = 0; r < 4; r++) {
          const int gr = m0 + wm * 64 + mt * 16 + g * 4 + r;
          dout[(size_t)gr * 1024 + gc] = acc[mt][nt][r] + bv;
        }
    }
  }
}

// ---------------- flash attention ----------------
// grid (32, 32) remapped; block 256 (4 waves x 16 q-rows), KVBLK=64.
// K/V staged in XOR-swizzled LDS via global_load_lds (pre-swizzled source),
// double-buffered, one barrier per tile. P per-wave swizzled tile.
__global__ __launch_bounds__(256, 4) void attn_kernel(
    const unsigned short* __restrict__ qb, const unsigned short* __restrict__ kb,
    const unsigned short* __restrict__ vtb, const int* __restrict__ cause,
    const int* __restrict__ effect, const float* __restrict__ strength,
    unsigned short* __restrict__ attb) {
  __shared__ unsigned short Ks[2][4096];  // [64 key][64 d] swizzled
  __shared__ unsigned short Vs[2][4096];  // [64 d][64 key] swizzled
  __shared__ unsigned short Pl[4][1024];  // per-wave [16 q][64 k] swizzled
  const int tid = threadIdx.x;
  const int w = tid >> 6, lane = tid & 63;
  const int g = lane >> 4, li = lane & 15;
  // XCD-bijective remap: all 32 q-blocks of one bh land on one XCD (lid%8 const)
  const int lid = blockIdx.y * 32 + blockIdx.x;
  const int bh = ((lid & 7) << 2) | ((lid >> 3) & 3);
  const int qblk = lid >> 5;
  const int b = bh >> 4, h = bh & 15;
  const int q0 = qblk * 64 + w * 16;

  const unsigned short* kbp = kb + (size_t)bh * 2048 * 64;
  const unsigned short* vbp = vtb + (size_t)bh * 64 * 2048;

  const unsigned short* qrow = qb + ((size_t)bh * 2048 + q0 + li) * 64 + g * 8;
  const bf16x8 qa0 = *(const bf16x8*)(qrow);
  const bf16x8 qa1 = *(const bf16x8*)(qrow + 32);

  int cm[4];
  #pragma unroll
  for (int r = 0; r < 4; r++) cm[r] = cause[b * 2048 + q0 + g * 4 + r];
  const float fmask = 1.0f - 0.5f * strength[0];
  const float c0s = 0.125f, c1s = 0.125f * fmask;
  const int* eff = effect + b * 2048;

  // staging geometry: 8 segments of 1KB (8 rows x 128B); source col pre-XORed
  const int seg0 = w * 2, seg1 = w * 2 + 1;
  const int r0 = seg0 * 8 + (lane >> 3), r1 = seg1 * 8 + (lane >> 3);
  const int cs = (((lane & 7) ^ (lane >> 3)) * 8);  // shorts
  const unsigned short* kg0 = kbp + (size_t)r0 * 64 + cs;
  const unsigned short* kg1 = kbp + (size_t)r1 * 64 + cs;
  const unsigned short* vg0 = vbp + (size_t)r0 * 2048 + cs;
  const unsigned short* vg1 = vbp + (size_t)r1 * 2048 + cs;

#define ASTAGE(bufi, t)                                        \
  {                                                            \
    gl_lds16(kg0 + (size_t)(t) * 4096, &Ks[bufi][seg0 * 512]); \
    gl_lds16(kg1 + (size_t)(t) * 4096, &Ks[bufi][seg1 * 512]); \
    gl_lds16(vg0 + (t) * 64, &Vs[bufi][seg0 * 512]);           \
    gl_lds16(vg1 + (t) * 64, &Vs[bufi][seg1 * 512]);           \
  }

  // swizzled frag-read columns (shorts): row&7 == li&7 for all frag reads
  const int swz = (li & 7) << 4;  // bytes
  const int col0 = ((g * 16) ^ swz) >> 1;
  const int col1 = ((64 + g * 16) ^ swz) >> 1;

  float m[4], l[4];
  f32x4 acc[4];
  #pragma unroll
  for (int r = 0; r < 4; r++) { m[r] = -1e30f; l[r] = 0.f; }
  #pragma unroll
  for (int c = 0; c < 4; c++) acc[c] = (f32x4){0.f, 0.f, 0.f, 0.f};

  ASTAGE(0, 0)
  int buf = 0;
  for (int t = 0; t < 32; t++) {
    __syncthreads();
    if (t + 1 < 32) ASTAGE(buf ^ 1, t + 1)
    const int kk = t * 64;
    // QK^T: 16q x 64k
    f32x4 s4[4];
    #pragma unroll
    for (int s = 0; s < 4; s++) {
      const bf16x8 kf0 = *(const bf16x8*)&Ks[buf][s * 1024 + li * 64 + col0];
      const bf16x8 kf1 = *(const bf16x8*)&Ks[buf][s * 1024 + li * 64 + col1];
      f32x4 z = (f32x4){0.f, 0.f, 0.f, 0.f};
      z = __builtin_amdgcn_mfma_f32_16x16x32_bf16(qa0, kf0, z, 0, 0, 0);
      z = __builtin_amdgcn_mfma_f32_16x16x32_bf16(qa1, kf1, z, 0, 0, 0);
      s4[s] = z;
    }
    int em[4];
    #pragma unroll
    for (int s = 0; s < 4; s++) em[s] = eff[kk + s * 16 + li];
    float sv[4][4];
    #pragma unroll
    for (int s = 0; s < 4; s++)
      #pragma unroll
      for (int r = 0; r < 4; r++)
        sv[s][r] = s4[s][r] * ((cm[r] & em[s]) ? c1s : c0s);
    float pm[4];
    #pragma unroll
    for (int r = 0; r < 4; r++)
      pm[r] = fmaxf(fmaxf(sv[0][r], sv[1][r]), fmaxf(sv[2][r], sv[3][r]));
    #pragma unroll
    for (int off = 1; off < 16; off <<= 1)
      #pragma unroll
      for (int r = 0; r < 4; r++) pm[r] = fmaxf(pm[r], __shfl_xor(pm[r], off, 16));
    int ok = 1;
    float nm[4];
    #pragma unroll
    for (int r = 0; r < 4; r++) {
      nm[r] = fmaxf(m[r], pm[r]);
      ok &= (pm[r] - m[r] <= 8.0f) ? 1 : 0;
    }
    if (!__all(ok)) {  // rescale only when a row max actually grew (T13)
      #pragma unroll
      for (int r = 0; r < 4; r++) {
        const float sc = __expf(m[r] - nm[r]);
        m[r] = nm[r]; l[r] *= sc;
        acc[0][r] *= sc; acc[1][r] *= sc; acc[2][r] *= sc; acc[3][r] *= sc;
      }
    }
    float ps[4];
    #pragma unroll
    for (int s = 0; s < 4; s++)
      #pragma unroll
      for (int r = 0; r < 4; r++) sv[s][r] = __expf(sv[s][r] - m[r]);
    #pragma unroll
    for (int r = 0; r < 4; r++)
      ps[r] = (sv[0][r] + sv[1][r]) + (sv[2][r] + sv[3][r]);
    #pragma unroll
    for (int off = 1; off < 16; off <<= 1)
      #pragma unroll
      for (int r = 0; r < 4; r++) ps[r] += __shfl_xor(ps[r], off, 16);
    #pragma unroll
    for (int r = 0; r < 4; r++) l[r] += ps[r];
    // P -> per-wave swizzled LDS tile (same-wave in-order DS, no barrier)
    #pragma unroll
    for (int s = 0; s < 4; s++)
      #pragma unroll
      for (int r = 0; r < 4; r++) {
        const int row = g * 4 + r;
        Pl[w][row * 64 + (((s * 32 + li * 2) ^ ((row & 7) << 4)) >> 1)] = f2b(sv[s][r]);
      }
    const bf16x8 pa0 = *(const bf16x8*)&Pl[w][li * 64 + col0];
    const bf16x8 pa1 = *(const bf16x8*)&Pl[w][li * 64 + col1];
    #pragma unroll
    for (int c = 0; c < 4; c++) {
      const bf16x8 vf0 = *(const bf16x8*)&Vs[buf][c * 1024 + li * 64 + col0];
      const bf16x8 vf1 = *(const bf16x8*)&Vs[buf][c * 1024 + li * 64 + col1];
      acc[c] = __builtin_amdgcn_mfma_f32_16x16x32_bf16(pa0, vf0, acc[c], 0, 0, 0);
      acc[c] = __builtin_amdgcn_mfma_f32_16x16x32_bf16(pa1, vf1, acc[c], 0, 0, 0);
    }
    buf ^= 1;
  }
#undef ASTAGE

  #pragma unroll
  for (int r = 0; r < 4; r++) l[r] = 1.0f / l[r];
  #pragma unroll
  for (int c = 0; c < 4; c++)
    #pragma unroll
    for (int r = 0; r < 4; r++) {
      const int row = q0 + g * 4 + r;
      attb[(size_t)(b * 2048 + row) * 1024 + h * 64 + c * 16 + li] = f2b(acc[c][r] * l[r]);
    }
}

// ---------------- launch ----------------

extern "C" void kernel_launch(void* const* d_in, const int* in_sizes, int n_in,
                              void* d_out, int out_size, void* d_ws, size_t ws_size,
                              hipStream_t stream) {
  (void)in_sizes; (void)n_in; (void)out_size; (void)ws_size;
  const float* x = (const float*)d_in[0];
  const int* cause = (const int*)d_in[1];
  const int* effect = (const int*)d_in[2];
  const float* strength = (const float*)d_in[3];
  const float* Wq = (const float*)d_in[4];
  const float* bq = (const float*)d_in[5];
  const float* Wk = (const float*)d_in[6];
  const float* bk = (const float*)d_in[7];
  const float* Wv = (const float*)d_in[8];
  const float* bv = (const float*)d_in[9];
  const float* Wo = (const float*)d_in[10];
  const float* bo = (const float*)d_in[11];
  float* out = (float*)d_out;

  char* ws = (char*)d_ws;
  unsigned short* xb  = (unsigned short*)(ws);                // 8 MB
  unsigned short* wqt = (unsigned short*)(ws + (8u << 20));   // 2 MB each, q|k|v contiguous
  unsigned short* wkt = (unsigned short*)(ws + (10u << 20));
  unsigned short* wvt = (unsigned short*)(ws + (12u << 20));
  unsigned short* wot = (unsigned short*)(ws + (14u << 20));
  unsigned short* qbf = (unsigned short*)(ws + (16u << 20));  // 8 MB
  unsigned short* kbf = (unsigned short*)(ws + (24u << 20));  // 8 MB
  unsigned short* vtb = (unsigned short*)(ws + (32u << 20));  // 8 MB
  unsigned short* attb = xb;  // reuse after projections

  cvt_x_kernel<<<4096, 256, 0, stream>>>(x, xb, 1048576);
  dim3 tg(32, 32), tb(32, 8);
  cvt_w_kernel<<<tg, tb, 0, stream>>>(Wq, wqt);
  cvt_w_kernel<<<tg, tb, 0, stream>>>(Wk, wkt);
  cvt_w_kernel<<<tg, tb, 0, stream>>>(Wv, wvt);
  cvt_w_kernel<<<tg, tb, 0, stream>>>(Wo, wot);

  // fused QKV projection: Bt = [wqt|wkt|wvt] = [3072][1024]
  gemm128<0><<<dim3(32, 24), 256, 0, stream>>>(xb, wqt, bq, bk, bv, qbf, kbf, vtb, nullptr);
  attn_kernel<<<dim3(32, 32), 256, 0, stream>>>(qbf, kbf, vtb, cause, effect, strength, attb);
  gemm128<1><<<dim3(32, 8), 256, 0, stream>>>(attb, wot, bo, nullptr, nullptr, nullptr, nullptr, nullptr, out);
}

// Round 5
// 268.186 us; speedup vs baseline: 1.5498x; 1.0359x over previous
//
#include <hip/hip_runtime.h>
#include <hip/hip_bf16.h>

// CausalInterventionAttention: B=2, S=2048, D=1024, H=16, HD=64
// Round 4: attn VALU trim (log2-domain softmax via v_exp_f32, native
// v_cvt_pk_bf16_f32 converts, cndmask-only mask select) + packed V stores.

typedef __attribute__((ext_vector_type(8))) short bf16x8;
typedef __attribute__((ext_vector_type(4))) float f32x4;

__device__ __forceinline__ unsigned short f2b(float f) {
  union { float f; unsigned u; } x; x.f = f;
  unsigned r = x.u + 0x7FFFu + ((x.u >> 16) & 1u);  // RNE
  return (unsigned short)(r >> 16);
}

// native cast -> single v_cvt_pk_bf16_f32 on gfx950 (RNE)
__device__ __forceinline__ unsigned short f2b_n(float f) {
  __hip_bfloat16 h = __float2bfloat16(f);
  union { __hip_bfloat16 h; unsigned short u; } c; c.h = h;
  return c.u;
}

__device__ __forceinline__ float fexp2(float x) {
#if __has_builtin(__builtin_amdgcn_exp2f)
  return __builtin_amdgcn_exp2f(x);
#else
  return __expf(x * 0.6931471805599453f);
#endif
}

__device__ __forceinline__ void gl_lds16(const unsigned short* g, unsigned short* l) {
  __builtin_amdgcn_global_load_lds(
      (const __attribute__((address_space(1))) unsigned int*)g,
      (__attribute__((address_space(3))) unsigned int*)l, 16, 0, 0);
}

// ---------------- conversion kernels ----------------

__global__ __launch_bounds__(256) void cvt_x_kernel(const float* __restrict__ x,
                                                    unsigned short* __restrict__ xb, int n4) {
  int i = blockIdx.x * 256 + threadIdx.x;
  if (i >= n4) return;
  float4 v = ((const float4*)x)[i];
  ushort4 o;
  o.x = f2b(v.x); o.y = f2b(v.y); o.z = f2b(v.z); o.w = f2b(v.w);
  ((ushort4*)xb)[i] = o;
}

// W [1024 k][1024 n] fp32 -> Wt [1024 n][1024 k] bf16
__global__ void cvt_w_kernel(const float* __restrict__ W, unsigned short* __restrict__ Wt) {
  __shared__ float t[32][33];
  const int k0 = blockIdx.x * 32, n0 = blockIdx.y * 32;
  const int tx = threadIdx.x, ty = threadIdx.y;  // block (32,8)
  #pragma unroll
  for (int i = 0; i < 32; i += 8)
    t[ty + i][tx] = W[(size_t)(k0 + ty + i) * 1024 + n0 + tx];
  __syncthreads();
  #pragma unroll
  for (int i = 0; i < 32; i += 8)
    Wt[(size_t)(n0 + ty + i) * 1024 + k0 + tx] = f2b(t[tx][ty + i]);
}

// ---------------- GEMM 128x128 (m97 structure) ----------------
// MODE 0: fused QKV (Bt = [3072 n][1024 k]); n-range selects dst q/k/vt + bias.
// MODE 1: out-proj, f32 row-major dst.
template <int MODE>
__global__ __launch_bounds__(256) void gemm128(
    const unsigned short* __restrict__ A, const unsigned short* __restrict__ Bt,
    const float* __restrict__ b0, const float* __restrict__ b1, const float* __restrict__ b2,
    unsigned short* __restrict__ dq, unsigned short* __restrict__ dk,
    unsigned short* __restrict__ dv, float* __restrict__ dout) {
  __shared__ unsigned short As[2][4096];  // [128][32]
  __shared__ unsigned short Bs[2][4096];  // [128][32]
  const int tid = threadIdx.x;
  const int w = tid >> 6, lane = tid & 63;
  const int li = lane & 15, g = lane >> 4;
  const int wm = w >> 1, wn = w & 1;
  const int m0 = blockIdx.x * 128, n0 = blockIdx.y * 128;

  const int seg0 = w * 2, seg1 = w * 2 + 1;
  const int srow0 = seg0 * 16 + (lane >> 2), srow1 = seg1 * 16 + (lane >> 2);
  const int scol = (lane & 3) * 8;
  const unsigned short* gA0 = A + (size_t)(m0 + srow0) * 1024 + scol;
  const unsigned short* gA1 = A + (size_t)(m0 + srow1) * 1024 + scol;
  const unsigned short* gB0 = Bt + (size_t)(n0 + srow0) * 1024 + scol;
  const unsigned short* gB1 = Bt + (size_t)(n0 + srow1) * 1024 + scol;

  f32x4 acc[4][4];
  #pragma unroll
  for (int i = 0; i < 4; i++)
    #pragma unroll
    for (int j = 0; j < 4; j++) acc[i][j] = (f32x4){0.f, 0.f, 0.f, 0.f};

#define GSTAGE(bufi, kt)                                 \
  {                                                      \
    const int ko = (kt) * 32;                            \
    gl_lds16(gA0 + ko, &As[bufi][seg0 * 512]);           \
    gl_lds16(gA1 + ko, &As[bufi][seg1 * 512]);           \
    gl_lds16(gB0 + ko, &Bs[bufi][seg0 * 512]);           \
    gl_lds16(gB1 + ko, &Bs[bufi][seg1 * 512]);           \
  }

  GSTAGE(0, 0)
  int buf = 0;
  for (int kt = 0; kt < 32; kt++) {
    __syncthreads();                    // stage(kt) landed; buf^1 free to overwrite
    if (kt + 1 < 32) GSTAGE(buf ^ 1, kt + 1)
    bf16x8 af[4], bfr[4];
    #pragma unroll
    for (int mt = 0; mt < 4; mt++)
      af[mt] = *(const bf16x8*)&As[buf][(wm * 64 + mt * 16 + li) * 32 + g * 8];
    #pragma unroll
    for (int nt = 0; nt < 4; nt++)
      bfr[nt] = *(const bf16x8*)&Bs[buf][(wn * 64 + nt * 16 + li) * 32 + g * 8];
    #pragma unroll
    for (int mt = 0; mt < 4; mt++)
      #pragma unroll
      for (int nt = 0; nt < 4; nt++)
        acc[mt][nt] = __builtin_amdgcn_mfma_f32_16x16x32_bf16(af[mt], bfr[nt], acc[mt][nt], 0, 0, 0);
    buf ^= 1;
  }
#undef GSTAGE

  if (MODE == 0) {
    const int sel = n0 >> 10;  // 128-tiles never straddle the 1024 boundaries
    const float* bp = sel == 0 ? b0 : (sel == 1 ? b1 : b2);
    unsigned short* dst = sel == 0 ? dq : (sel == 1 ? dk : dv);
    #pragma unroll
    for (int nt = 0; nt < 4; nt++) {
      const int gc = n0 + wn * 64 + nt * 16 + li;
      const int c = gc & 1023, h = c >> 6, d = c & 63;
      const float bv = bp[c];
      #pragma unroll
      for (int mt = 0; mt < 4; mt++) {
        const int base = m0 + wm * 64 + mt * 16 + g * 4;  // 4-aligned, no 2048-straddle
        const int bb = base >> 11, s = base & 2047;
        if (sel < 2) {
          #pragma unroll
          for (int r = 0; r < 4; r++)
            dst[((size_t)(bb * 16 + h) * 2048 + s + r) * 64 + d] = f2b_n(acc[mt][nt][r] + bv);
        } else {  // Vt [bh][d][s]: 4 consecutive s -> one 8B store
          ushort4 pk;
          pk.x = f2b_n(acc[mt][nt][0] + bv);
          pk.y = f2b_n(acc[mt][nt][1] + bv);
          pk.z = f2b_n(acc[mt][nt][2] + bv);
          pk.w = f2b_n(acc[mt][nt][3] + bv);
          *(ushort4*)&dst[((size_t)(bb * 16 + h) * 64 + d) * 2048 + s] = pk;
        }
      }
    }
  } else {
    #pragma unroll
    for (int nt = 0; nt < 4; nt++) {
      const int gc = n0 + wn * 64 + nt * 16 + li;
      const float bv = b0[gc];
      #pragma unroll
      for (int mt = 0; mt < 4; mt++)
        #pragma unroll
        for (int r = 0; r < 4; r++) {
          const int gr = m0 + wm * 64 + mt * 16 + g * 4 + r;
          dout[(size_t)gr * 1024 + gc] = acc[mt][nt][r] + bv;
        }
    }
  }
}

// ---------------- flash attention ----------------
// grid (32, 32) remapped; block 256 (4 waves x 16 q-rows), KVBLK=64.
// Softmax tracked in log2 domain (scores pre-scaled by log2e); v_exp_f32 = 2^x.
__global__ __launch_bounds__(256, 4) void attn_kernel(
    const unsigned short* __restrict__ qb, const unsigned short* __restrict__ kb,
    const unsigned short* __restrict__ vtb, const int* __restrict__ cause,
    const int* __restrict__ effect, const float* __restrict__ strength,
    unsigned short* __restrict__ attb) {
  __shared__ unsigned short Ks[2][4096];  // [64 key][64 d] swizzled
  __shared__ unsigned short Vs[2][4096];  // [64 d][64 key] swizzled
  __shared__ unsigned short Pl[4][1024];  // per-wave [16 q][64 k] swizzled
  const int tid = threadIdx.x;
  const int w = tid >> 6, lane = tid & 63;
  const int g = lane >> 4, li = lane & 15;
  // XCD-bijective remap: all 32 q-blocks of one bh land on one XCD (lid%8 const)
  const int lid = blockIdx.y * 32 + blockIdx.x;
  const int bh = ((lid & 7) << 2) | ((lid >> 3) & 3);
  const int qblk = lid >> 5;
  const int b = bh >> 4, h = bh & 15;
  const int q0 = qblk * 64 + w * 16;

  const unsigned short* kbp = kb + (size_t)bh * 2048 * 64;
  const unsigned short* vbp = vtb + (size_t)bh * 64 * 2048;

  const unsigned short* qrow = qb + ((size_t)bh * 2048 + q0 + li) * 64 + g * 8;
  const bf16x8 qa0 = *(const bf16x8*)(qrow);
  const bf16x8 qa1 = *(const bf16x8*)(qrow + 32);

  int cm[4];
  #pragma unroll
  for (int r = 0; r < 4; r++) cm[r] = cause[b * 2048 + q0 + g * 4 + r];
  const float LOG2E = 1.44269504f;
  const float fmask = 1.0f - 0.5f * strength[0];
  const float c0s2 = 0.125f * LOG2E;          // score scale, log2 domain
  const float c1s2 = c0s2 * fmask;
  float mrr[4];
  #pragma unroll
  for (int r = 0; r < 4; r++) mrr[r] = cm[r] ? c1s2 : c0s2;
  const int* eff = effect + b * 2048;

  // staging geometry: 8 segments of 1KB (8 rows x 128B); source col pre-XORed
  const int seg0 = w * 2, seg1 = w * 2 + 1;
  const int r0 = seg0 * 8 + (lane >> 3), r1 = seg1 * 8 + (lane >> 3);
  const int cs = (((lane & 7) ^ (lane >> 3)) * 8);  // shorts
  const unsigned short* kg0 = kbp + (size_t)r0 * 64 + cs;
  const unsigned short* kg1 = kbp + (size_t)r1 * 64 + cs;
  const unsigned short* vg0 = vbp + (size_t)r0 * 2048 + cs;
  const unsigned short* vg1 = vbp + (size_t)r1 * 2048 + cs;

#define ASTAGE(bufi, t)                                        \
  {                                                            \
    gl_lds16(kg0 + (size_t)(t) * 4096, &Ks[bufi][seg0 * 512]); \
    gl_lds16(kg1 + (size_t)(t) * 4096, &Ks[bufi][seg1 * 512]); \
    gl_lds16(vg0 + (t) * 64, &Vs[bufi][seg0 * 512]);           \
    gl_lds16(vg1 + (t) * 64, &Vs[bufi][seg1 * 512]);           \
  }

  // swizzled frag-read columns (shorts): row&7 == li&7 for all frag reads
  const int swz = (li & 7) << 4;  // bytes
  const int col0 = ((g * 16) ^ swz) >> 1;
  const int col1 = ((64 + g * 16) ^ swz) >> 1;

  float m[4], l[4];
  f32x4 acc[4];
  #pragma unroll
  for (int r = 0; r < 4; r++) { m[r] = -1e30f; l[r] = 0.f; }
  #pragma unroll
  for (int c = 0; c < 4; c++) acc[c] = (f32x4){0.f, 0.f, 0.f, 0.f};

  ASTAGE(0, 0)
  int buf = 0;
  for (int t = 0; t < 32; t++) {
    __syncthreads();
    if (t + 1 < 32) ASTAGE(buf ^ 1, t + 1)
    const int kk = t * 64;
    // QK^T: 16q x 64k
    f32x4 s4[4];
    #pragma unroll
    for (int s = 0; s < 4; s++) {
      const bf16x8 kf0 = *(const bf16x8*)&Ks[buf][s * 1024 + li * 64 + col0];
      const bf16x8 kf1 = *(const bf16x8*)&Ks[buf][s * 1024 + li * 64 + col1];
      f32x4 z = (f32x4){0.f, 0.f, 0.f, 0.f};
      z = __builtin_amdgcn_mfma_f32_16x16x32_bf16(qa0, kf0, z, 0, 0, 0);
      z = __builtin_amdgcn_mfma_f32_16x16x32_bf16(qa1, kf1, z, 0, 0, 0);
      s4[s] = z;
    }
    int em[4];
    #pragma unroll
    for (int s = 0; s < 4; s++) em[s] = eff[kk + s * 16 + li];
    float sv[4][4];
    #pragma unroll
    for (int s = 0; s < 4; s++) {
      const bool eb = em[s] != 0;
      #pragma unroll
      for (int r = 0; r < 4; r++)
        sv[s][r] = s4[s][r] * (eb ? mrr[r] : c0s2);
    }
    float pm[4];
    #pragma unroll
    for (int r = 0; r < 4; r++)
      pm[r] = fmaxf(fmaxf(sv[0][r], sv[1][r]), fmaxf(sv[2][r], sv[3][r]));
    #pragma unroll
    for (int off = 1; off < 16; off <<= 1)
      #pragma unroll
      for (int r = 0; r < 4; r++) pm[r] = fmaxf(pm[r], __shfl_xor(pm[r], off, 16));
    int ok = 1;
    float nm[4];
    #pragma unroll
    for (int r = 0; r < 4; r++) {
      nm[r] = fmaxf(m[r], pm[r]);
      ok &= (pm[r] - m[r] <= 11.5f) ? 1 : 0;  // ~8 in ln-domain
    }
    if (!__all(ok)) {  // rescale only when a row max actually grew (T13)
      #pragma unroll
      for (int r = 0; r < 4; r++) {
        const float sc = fexp2(m[r] - nm[r]);
        m[r] = nm[r]; l[r] *= sc;
        acc[0][r] *= sc; acc[1][r] *= sc; acc[2][r] *= sc; acc[3][r] *= sc;
      }
    }
    float ps[4];
    #pragma unroll
    for (int s = 0; s < 4; s++)
      #pragma unroll
      for (int r = 0; r < 4; r++) sv[s][r] = fexp2(sv[s][r] - m[r]);
    #pragma unroll
    for (int r = 0; r < 4; r++)
      ps[r] = (sv[0][r] + sv[1][r]) + (sv[2][r] + sv[3][r]);
    #pragma unroll
    for (int off = 1; off < 16; off <<= 1)
      #pragma unroll
      for (int r = 0; r < 4; r++) ps[r] += __shfl_xor(ps[r], off, 16);
    #pragma unroll
    for (int r = 0; r < 4; r++) l[r] += ps[r];
    // P -> per-wave swizzled LDS tile (same-wave in-order DS, no barrier)
    #pragma unroll
    for (int s = 0; s < 4; s++)
      #pragma unroll
      for (int r = 0; r < 4; r++) {
        const int row = g * 4 + r;
        Pl[w][row * 64 + (((s * 32 + li * 2) ^ ((row & 7) << 4)) >> 1)] = f2b_n(sv[s][r]);
      }
    const bf16x8 pa0 = *(const bf16x8*)&Pl[w][li * 64 + col0];
    const bf16x8 pa1 = *(const bf16x8*)&Pl[w][li * 64 + col1];
    #pragma unroll
    for (int c = 0; c < 4; c++) {
      const bf16x8 vf0 = *(const bf16x8*)&Vs[buf][c * 1024 + li * 64 + col0];
      const bf16x8 vf1 = *(const bf16x8*)&Vs[buf][c * 1024 + li * 64 + col1];
      acc[c] = __builtin_amdgcn_mfma_f32_16x16x32_bf16(pa0, vf0, acc[c], 0, 0, 0);
      acc[c] = __builtin_amdgcn_mfma_f32_16x16x32_bf16(pa1, vf1, acc[c], 0, 0, 0);
    }
    buf ^= 1;
  }
#undef ASTAGE

  #pragma unroll
  for (int r = 0; r < 4; r++) l[r] = 1.0f / l[r];
  #pragma unroll
  for (int c = 0; c < 4; c++)
    #pragma unroll
    for (int r = 0; r < 4; r++) {
      const int row = q0 + g * 4 + r;
      attb[(size_t)(b * 2048 + row) * 1024 + h * 64 + c * 16 + li] = f2b_n(acc[c][r] * l[r]);
    }
}

// ---------------- launch ----------------

extern "C" void kernel_launch(void* const* d_in, const int* in_sizes, int n_in,
                              void* d_out, int out_size, void* d_ws, size_t ws_size,
                              hipStream_t stream) {
  (void)in_sizes; (void)n_in; (void)out_size; (void)ws_size;
  const float* x = (const float*)d_in[0];
  const int* cause = (const int*)d_in[1];
  const int* effect = (const int*)d_in[2];
  const float* strength = (const float*)d_in[3];
  const float* Wq = (const float*)d_in[4];
  const float* bq = (const float*)d_in[5];
  const float* Wk = (const float*)d_in[6];
  const float* bk = (const float*)d_in[7];
  const float* Wv = (const float*)d_in[8];
  const float* bv = (const float*)d_in[9];
  const float* Wo = (const float*)d_in[10];
  const float* bo = (const float*)d_in[11];
  float* out = (float*)d_out;

  char* ws = (char*)d_ws;
  unsigned short* xb  = (unsigned short*)(ws);                // 8 MB
  unsigned short* wqt = (unsigned short*)(ws + (8u << 20));   // 2 MB each, q|k|v contiguous
  unsigned short* wkt = (unsigned short*)(ws + (10u << 20));
  unsigned short* wvt = (unsigned short*)(ws + (12u << 20));
  unsigned short* wot = (unsigned short*)(ws + (14u << 20));
  unsigned short* qbf = (unsigned short*)(ws + (16u << 20));  // 8 MB
  unsigned short* kbf = (unsigned short*)(ws + (24u << 20));  // 8 MB
  unsigned short* vtb = (unsigned short*)(ws + (32u << 20));  // 8 MB
  unsigned short* attb = xb;  // reuse after projections

  cvt_x_kernel<<<4096, 256, 0, stream>>>(x, xb, 1048576);
  dim3 tg(32, 32), tb(32, 8);
  cvt_w_kernel<<<tg, tb, 0, stream>>>(Wq, wqt);
  cvt_w_kernel<<<tg, tb, 0, stream>>>(Wk, wkt);
  cvt_w_kernel<<<tg, tb, 0, stream>>>(Wv, wvt);
  cvt_w_kernel<<<tg, tb, 0, stream>>>(Wo, wot);

  // fused QKV projection: Bt = [wqt|wkt|wvt] = [3072][1024]
  gemm128<0><<<dim3(32, 24), 256, 0, stream>>>(xb, wqt, bq, bk, bv, qbf, kbf, vtb, nullptr);
  attn_kernel<<<dim3(32, 32), 256, 0, stream>>>(qbf, kbf, vtb, cause, effect, strength, attb);
  gemm128<1><<<dim3(32, 8), 256, 0, stream>>>(attb, wot, bo, nullptr, nullptr, nullptr, nullptr, nullptr, out);
}

// Round 6
// 225.457 us; speedup vs baseline: 1.8435x; 1.1895x over previous
//
#include <hip/hip_runtime.h>
#include <hip/hip_bf16.h>

// CausalInterventionAttention: B=2, S=2048, D=1024, H=16, HD=64
// Round 5: max-free fixed-shift softmax (scores bounded -> no running max,
// no per-tile cross-lane reduces; single final l-reduce), fused cvt_w4.

typedef __attribute__((ext_vector_type(8))) short bf16x8;
typedef __attribute__((ext_vector_type(4))) float f32x4;

__device__ __forceinline__ unsigned short f2b(float f) {
  union { float f; unsigned u; } x; x.f = f;
  unsigned r = x.u + 0x7FFFu + ((x.u >> 16) & 1u);  // RNE
  return (unsigned short)(r >> 16);
}

// native cast -> v_cvt_pk-able bf16 (RNE)
__device__ __forceinline__ unsigned short f2b_n(float f) {
  __hip_bfloat16 h = __float2bfloat16(f);
  union { __hip_bfloat16 h; unsigned short u; } c; c.h = h;
  return c.u;
}

__device__ __forceinline__ float fexp2(float x) {
#if __has_builtin(__builtin_amdgcn_exp2f)
  return __builtin_amdgcn_exp2f(x);
#else
  return __expf(x * 0.6931471805599453f);
#endif
}

__device__ __forceinline__ void gl_lds16(const unsigned short* g, unsigned short* l) {
  __builtin_amdgcn_global_load_lds(
      (const __attribute__((address_space(1))) unsigned int*)g,
      (__attribute__((address_space(3))) unsigned int*)l, 16, 0, 0);
}

// ---------------- conversion kernels ----------------

__global__ __launch_bounds__(256) void cvt_x_kernel(const float* __restrict__ x,
                                                    unsigned short* __restrict__ xb, int n4) {
  int i = blockIdx.x * 256 + threadIdx.x;
  if (i >= n4) return;
  float4 v = ((const float4*)x)[i];
  ushort4 o;
  o.x = f2b(v.x); o.y = f2b(v.y); o.z = f2b(v.z); o.w = f2b(v.w);
  ((ushort4*)xb)[i] = o;
}

// All 4 weights: W [1024 k][1024 n] fp32 -> Wt [1024 n][1024 k] bf16 (packed writes)
__global__ __launch_bounds__(256) void cvt_w4_kernel(
    const float* __restrict__ W0, const float* __restrict__ W1,
    const float* __restrict__ W2, const float* __restrict__ W3,
    unsigned short* __restrict__ WtBase) {
  __shared__ float t[64][33];
  const int z = blockIdx.z;
  const float* W = z == 0 ? W0 : (z == 1 ? W1 : (z == 2 ? W2 : W3));
  unsigned short* Wt = WtBase + (size_t)z * 1048576;
  const int k0 = blockIdx.x * 64, n0 = blockIdx.y * 32;
  const int tx = threadIdx.x, ty = threadIdx.y;  // block (32,8)
  #pragma unroll
  for (int i = 0; i < 8; i++)
    t[ty + i * 8][tx] = W[(size_t)(k0 + ty + i * 8) * 1024 + n0 + tx];
  __syncthreads();
  #pragma unroll
  for (int i = 0; i < 4; i++) {
    const int n = ty + i * 8;
    ushort2 pk;
    pk.x = f2b(t[tx * 2][n]);
    pk.y = f2b(t[tx * 2 + 1][n]);
    *(ushort2*)&Wt[(size_t)(n0 + n) * 1024 + k0 + tx * 2] = pk;
  }
}

// ---------------- GEMM 128x128 (m97 structure) ----------------
// MODE 0: fused QKV (Bt = [3072 n][1024 k]); n-range selects dst q/k/vt + bias.
// MODE 1: out-proj, f32 row-major dst.
template <int MODE>
__global__ __launch_bounds__(256) void gemm128(
    const unsigned short* __restrict__ A, const unsigned short* __restrict__ Bt,
    const float* __restrict__ b0, const float* __restrict__ b1, const float* __restrict__ b2,
    unsigned short* __restrict__ dq, unsigned short* __restrict__ dk,
    unsigned short* __restrict__ dv, float* __restrict__ dout) {
  __shared__ unsigned short As[2][4096];  // [128][32]
  __shared__ unsigned short Bs[2][4096];  // [128][32]
  const int tid = threadIdx.x;
  const int w = tid >> 6, lane = tid & 63;
  const int li = lane & 15, g = lane >> 4;
  const int wm = w >> 1, wn = w & 1;
  const int m0 = blockIdx.x * 128, n0 = blockIdx.y * 128;

  const int seg0 = w * 2, seg1 = w * 2 + 1;
  const int srow0 = seg0 * 16 + (lane >> 2), srow1 = seg1 * 16 + (lane >> 2);
  const int scol = (lane & 3) * 8;
  const unsigned short* gA0 = A + (size_t)(m0 + srow0) * 1024 + scol;
  const unsigned short* gA1 = A + (size_t)(m0 + srow1) * 1024 + scol;
  const unsigned short* gB0 = Bt + (size_t)(n0 + srow0) * 1024 + scol;
  const unsigned short* gB1 = Bt + (size_t)(n0 + srow1) * 1024 + scol;

  f32x4 acc[4][4];
  #pragma unroll
  for (int i = 0; i < 4; i++)
    #pragma unroll
    for (int j = 0; j < 4; j++) acc[i][j] = (f32x4){0.f, 0.f, 0.f, 0.f};

#define GSTAGE(bufi, kt)                                 \
  {                                                      \
    const int ko = (kt) * 32;                            \
    gl_lds16(gA0 + ko, &As[bufi][seg0 * 512]);           \
    gl_lds16(gA1 + ko, &As[bufi][seg1 * 512]);           \
    gl_lds16(gB0 + ko, &Bs[bufi][seg0 * 512]);           \
    gl_lds16(gB1 + ko, &Bs[bufi][seg1 * 512]);           \
  }

  GSTAGE(0, 0)
  int buf = 0;
  for (int kt = 0; kt < 32; kt++) {
    __syncthreads();                    // stage(kt) landed; buf^1 free to overwrite
    if (kt + 1 < 32) GSTAGE(buf ^ 1, kt + 1)
    bf16x8 af[4], bfr[4];
    #pragma unroll
    for (int mt = 0; mt < 4; mt++)
      af[mt] = *(const bf16x8*)&As[buf][(wm * 64 + mt * 16 + li) * 32 + g * 8];
    #pragma unroll
    for (int nt = 0; nt < 4; nt++)
      bfr[nt] = *(const bf16x8*)&Bs[buf][(wn * 64 + nt * 16 + li) * 32 + g * 8];
    #pragma unroll
    for (int mt = 0; mt < 4; mt++)
      #pragma unroll
      for (int nt = 0; nt < 4; nt++)
        acc[mt][nt] = __builtin_amdgcn_mfma_f32_16x16x32_bf16(af[mt], bfr[nt], acc[mt][nt], 0, 0, 0);
    buf ^= 1;
  }
#undef GSTAGE

  if (MODE == 0) {
    const int sel = n0 >> 10;  // 128-tiles never straddle the 1024 boundaries
    const float* bp = sel == 0 ? b0 : (sel == 1 ? b1 : b2);
    unsigned short* dst = sel == 0 ? dq : (sel == 1 ? dk : dv);
    #pragma unroll
    for (int nt = 0; nt < 4; nt++) {
      const int gc = n0 + wn * 64 + nt * 16 + li;
      const int c = gc & 1023, h = c >> 6, d = c & 63;
      const float bv = bp[c];
      #pragma unroll
      for (int mt = 0; mt < 4; mt++) {
        const int base = m0 + wm * 64 + mt * 16 + g * 4;  // 4-aligned, no 2048-straddle
        const int bb = base >> 11, s = base & 2047;
        if (sel < 2) {
          #pragma unroll
          for (int r = 0; r < 4; r++)
            dst[((size_t)(bb * 16 + h) * 2048 + s + r) * 64 + d] = f2b_n(acc[mt][nt][r] + bv);
        } else {  // Vt [bh][d][s]: 4 consecutive s -> one 8B store
          ushort4 pk;
          pk.x = f2b_n(acc[mt][nt][0] + bv);
          pk.y = f2b_n(acc[mt][nt][1] + bv);
          pk.z = f2b_n(acc[mt][nt][2] + bv);
          pk.w = f2b_n(acc[mt][nt][3] + bv);
          *(ushort4*)&dst[((size_t)(bb * 16 + h) * 64 + d) * 2048 + s] = pk;
        }
      }
    }
  } else {
    #pragma unroll
    for (int nt = 0; nt < 4; nt++) {
      const int gc = n0 + wn * 64 + nt * 16 + li;
      const float bv = b0[gc];
      #pragma unroll
      for (int mt = 0; mt < 4; mt++)
        #pragma unroll
        for (int r = 0; r < 4; r++) {
          const int gr = m0 + wm * 64 + mt * 16 + g * 4 + r;
          dout[(size_t)gr * 1024 + gc] = acc[mt][nt][r] + bv;
        }
    }
  }
}

// ---------------- flash attention ----------------
// grid (32, 32) remapped; block 256 (4 waves x 16 q-rows), KVBLK=64.
// Max-free softmax: scores bounded (|q·k/8·log2e| << 127), so p = exp2(score*c)
// with fixed shift 0 is exact softmax after normalization. No in-loop reduces.
__global__ __launch_bounds__(256, 4) void attn_kernel(
    const unsigned short* __restrict__ qb, const unsigned short* __restrict__ kb,
    const unsigned short* __restrict__ vtb, const int* __restrict__ cause,
    const int* __restrict__ effect, const float* __restrict__ strength,
    unsigned short* __restrict__ attb) {
  __shared__ unsigned short Ks[2][4096];  // [64 key][64 d] swizzled
  __shared__ unsigned short Vs[2][4096];  // [64 d][64 key] swizzled
  __shared__ unsigned short Pl[4][1024];  // per-wave [16 q][64 k] swizzled
  const int tid = threadIdx.x;
  const int w = tid >> 6, lane = tid & 63;
  const int g = lane >> 4, li = lane & 15;
  // XCD-bijective remap: all 32 q-blocks of one bh land on one XCD (lid%8 const)
  const int lid = blockIdx.y * 32 + blockIdx.x;
  const int bh = ((lid & 7) << 2) | ((lid >> 3) & 3);
  const int qblk = lid >> 5;
  const int b = bh >> 4, h = bh & 15;
  const int q0 = qblk * 64 + w * 16;

  const unsigned short* kbp = kb + (size_t)bh * 2048 * 64;
  const unsigned short* vbp = vtb + (size_t)bh * 64 * 2048;

  const unsigned short* qrow = qb + ((size_t)bh * 2048 + q0 + li) * 64 + g * 8;
  const bf16x8 qa0 = *(const bf16x8*)(qrow);
  const bf16x8 qa1 = *(const bf16x8*)(qrow + 32);

  int cm[4];
  #pragma unroll
  for (int r = 0; r < 4; r++) cm[r] = cause[b * 2048 + q0 + g * 4 + r];
  const float LOG2E = 1.44269504f;
  const float fmask = 1.0f - 0.5f * strength[0];
  const float c0s2 = 0.125f * LOG2E;          // score scale, log2 domain
  const float c1s2 = c0s2 * fmask;
  float mrr[4];
  #pragma unroll
  for (int r = 0; r < 4; r++) mrr[r] = cm[r] ? c1s2 : c0s2;
  const int* eff = effect + b * 2048;

  // staging geometry: 8 segments of 1KB (8 rows x 128B); source col pre-XORed
  const int seg0 = w * 2, seg1 = w * 2 + 1;
  const int r0 = seg0 * 8 + (lane >> 3), r1 = seg1 * 8 + (lane >> 3);
  const int cs = (((lane & 7) ^ (lane >> 3)) * 8);  // shorts
  const unsigned short* kg0 = kbp + (size_t)r0 * 64 + cs;
  const unsigned short* kg1 = kbp + (size_t)r1 * 64 + cs;
  const unsigned short* vg0 = vbp + (size_t)r0 * 2048 + cs;
  const unsigned short* vg1 = vbp + (size_t)r1 * 2048 + cs;

#define ASTAGE(bufi, t)                                        \
  {                                                            \
    gl_lds16(kg0 + (size_t)(t) * 4096, &Ks[bufi][seg0 * 512]); \
    gl_lds16(kg1 + (size_t)(t) * 4096, &Ks[bufi][seg1 * 512]); \
    gl_lds16(vg0 + (t) * 64, &Vs[bufi][seg0 * 512]);           \
    gl_lds16(vg1 + (t) * 64, &Vs[bufi][seg1 * 512]);           \
  }

  // swizzled frag-read columns (shorts): row&7 == li&7 for all frag reads
  const int swz = (li & 7) << 4;  // bytes
  const int col0 = ((g * 16) ^ swz) >> 1;
  const int col1 = ((64 + g * 16) ^ swz) >> 1;

  float l[4];
  f32x4 acc[4];
  #pragma unroll
  for (int r = 0; r < 4; r++) l[r] = 0.f;
  #pragma unroll
  for (int c = 0; c < 4; c++) acc[c] = (f32x4){0.f, 0.f, 0.f, 0.f};

  ASTAGE(0, 0)
  int buf = 0;
  for (int t = 0; t < 32; t++) {
    __syncthreads();
    if (t + 1 < 32) ASTAGE(buf ^ 1, t + 1)
    const int kk = t * 64;
    // QK^T: 16q x 64k
    f32x4 s4[4];
    #pragma unroll
    for (int s = 0; s < 4; s++) {
      const bf16x8 kf0 = *(const bf16x8*)&Ks[buf][s * 1024 + li * 64 + col0];
      const bf16x8 kf1 = *(const bf16x8*)&Ks[buf][s * 1024 + li * 64 + col1];
      f32x4 z = (f32x4){0.f, 0.f, 0.f, 0.f};
      z = __builtin_amdgcn_mfma_f32_16x16x32_bf16(qa0, kf0, z, 0, 0, 0);
      z = __builtin_amdgcn_mfma_f32_16x16x32_bf16(qa1, kf1, z, 0, 0, 0);
      s4[s] = z;
    }
    // p = exp2(score * c); per-lane partial row-sums (no cross-lane ops)
    float sv[4][4];
    #pragma unroll
    for (int s = 0; s < 4; s++) {
      const bool eb = eff[kk + s * 16 + li] != 0;
      #pragma unroll
      for (int r = 0; r < 4; r++) {
        sv[s][r] = fexp2(s4[s][r] * (eb ? mrr[r] : c0s2));
        l[r] += sv[s][r];
      }
    }
    // P -> per-wave swizzled LDS tile (same-wave in-order DS, no barrier)
    #pragma unroll
    for (int s = 0; s < 4; s++)
      #pragma unroll
      for (int r = 0; r < 4; r++) {
        const int row = g * 4 + r;
        Pl[w][row * 64 + (((s * 32 + li * 2) ^ ((row & 7) << 4)) >> 1)] = f2b_n(sv[s][r]);
      }
    const bf16x8 pa0 = *(const bf16x8*)&Pl[w][li * 64 + col0];
    const bf16x8 pa1 = *(const bf16x8*)&Pl[w][li * 64 + col1];
    #pragma unroll
    for (int c = 0; c < 4; c++) {
      const bf16x8 vf0 = *(const bf16x8*)&Vs[buf][c * 1024 + li * 64 + col0];
      const bf16x8 vf1 = *(const bf16x8*)&Vs[buf][c * 1024 + li * 64 + col1];
      acc[c] = __builtin_amdgcn_mfma_f32_16x16x32_bf16(pa0, vf0, acc[c], 0, 0, 0);
      acc[c] = __builtin_amdgcn_mfma_f32_16x16x32_bf16(pa1, vf1, acc[c], 0, 0, 0);
    }
    buf ^= 1;
  }
#undef ASTAGE

  // single final l-reduce across the 16 lanes of each group
  #pragma unroll
  for (int off = 1; off < 16; off <<= 1)
    #pragma unroll
    for (int r = 0; r < 4; r++) l[r] += __shfl_xor(l[r], off, 16);
  #pragma unroll
  for (int r = 0; r < 4; r++) l[r] = 1.0f / l[r];
  #pragma unroll
  for (int c = 0; c < 4; c++)
    #pragma unroll
    for (int r = 0; r < 4; r++) {
      const int row = q0 + g * 4 + r;
      attb[(size_t)(b * 2048 + row) * 1024 + h * 64 + c * 16 + li] = f2b_n(acc[c][r] * l[r]);
    }
}

// ---------------- launch ----------------

extern "C" void kernel_launch(void* const* d_in, const int* in_sizes, int n_in,
                              void* d_out, int out_size, void* d_ws, size_t ws_size,
                              hipStream_t stream) {
  (void)in_sizes; (void)n_in; (void)out_size; (void)ws_size;
  const float* x = (const float*)d_in[0];
  const int* cause = (const int*)d_in[1];
  const int* effect = (const int*)d_in[2];
  const float* strength = (const float*)d_in[3];
  const float* Wq = (const float*)d_in[4];
  const float* bq = (const float*)d_in[5];
  const float* Wk = (const float*)d_in[6];
  const float* bk = (const float*)d_in[7];
  const float* Wv = (const float*)d_in[8];
  const float* bv = (const float*)d_in[9];
  const float* Wo = (const float*)d_in[10];
  const float* bo = (const float*)d_in[11];
  float* out = (float*)d_out;

  char* ws = (char*)d_ws;
  unsigned short* xb  = (unsigned short*)(ws);                // 8 MB
  unsigned short* wqt = (unsigned short*)(ws + (8u << 20));   // 2 MB each, q|k|v|o contiguous
  unsigned short* qbf = (unsigned short*)(ws + (16u << 20));  // 8 MB
  unsigned short* kbf = (unsigned short*)(ws + (24u << 20));  // 8 MB
  unsigned short* vtb = (unsigned short*)(ws + (32u << 20));  // 8 MB
  unsigned short* wot = wqt + 3u * 1048576u;
  unsigned short* attb = xb;  // reuse after projections

  cvt_x_kernel<<<4096, 256, 0, stream>>>(x, xb, 1048576);
  cvt_w4_kernel<<<dim3(16, 32, 4), dim3(32, 8), 0, stream>>>(Wq, Wk, Wv, Wo, wqt);

  // fused QKV projection: Bt = [wqt|wkt|wvt] = [3072][1024]
  gemm128<0><<<dim3(32, 24), 256, 0, stream>>>(xb, wqt, bq, bk, bv, qbf, kbf, vtb, nullptr);
  attn_kernel<<<dim3(32, 32), 256, 0, stream>>>(qbf, kbf, vtb, cause, effect, strength, attb);
  gemm128<1><<<dim3(32, 8), 256, 0, stream>>>(attb, wot, bo, nullptr, nullptr, nullptr, nullptr, nullptr, out);
}

// Round 10
// 219.629 us; speedup vs baseline: 1.8924x; 1.0265x over previous
//
#include <hip/hip_runtime.h>
#include <hip/hip_bf16.h>

// CausalInterventionAttention: B=2, S=2048, D=1024, H=16, HD=64
// Round 9 == Round 6 (never measured): attn QBLK=32/wave, out-proj 128x64.

typedef __attribute__((ext_vector_type(8))) short bf16x8;
typedef __attribute__((ext_vector_type(4))) float f32x4;

__device__ __forceinline__ unsigned short f2b(float f) {
  union { float f; unsigned u; } x; x.f = f;
  unsigned r = x.u + 0x7FFFu + ((x.u >> 16) & 1u);  // RNE
  return (unsigned short)(r >> 16);
}

__device__ __forceinline__ unsigned short f2b_n(float f) {
  __hip_bfloat16 h = __float2bfloat16(f);
  union { __hip_bfloat16 h; unsigned short u; } c; c.h = h;
  return c.u;
}

__device__ __forceinline__ float fexp2(float x) {
#if __has_builtin(__builtin_amdgcn_exp2f)
  return __builtin_amdgcn_exp2f(x);
#else
  return __expf(x * 0.6931471805599453f);
#endif
}

__device__ __forceinline__ void gl_lds16(const unsigned short* g, unsigned short* l) {
  __builtin_amdgcn_global_load_lds(
      (const __attribute__((address_space(1))) unsigned int*)g,
      (__attribute__((address_space(3))) unsigned int*)l, 16, 0, 0);
}

// ---------------- conversion kernels ----------------

__global__ __launch_bounds__(256) void cvt_x_kernel(const float* __restrict__ x,
                                                    unsigned short* __restrict__ xb, int n4) {
  int i = blockIdx.x * 256 + threadIdx.x;
  if (i >= n4) return;
  float4 v = ((const float4*)x)[i];
  ushort4 o;
  o.x = f2b(v.x); o.y = f2b(v.y); o.z = f2b(v.z); o.w = f2b(v.w);
  ((ushort4*)xb)[i] = o;
}

// All 4 weights: W [1024 k][1024 n] fp32 -> Wt [1024 n][1024 k] bf16 (packed writes)
__global__ __launch_bounds__(256) void cvt_w4_kernel(
    const float* __restrict__ W0, const float* __restrict__ W1,
    const float* __restrict__ W2, const float* __restrict__ W3,
    unsigned short* __restrict__ WtBase) {
  __shared__ float t[64][33];
  const int z = blockIdx.z;
  const float* W = z == 0 ? W0 : (z == 1 ? W1 : (z == 2 ? W2 : W3));
  unsigned short* Wt = WtBase + (size_t)z * 1048576;
  const int k0 = blockIdx.x * 64, n0 = blockIdx.y * 32;
  const int tx = threadIdx.x, ty = threadIdx.y;  // block (32,8)
  #pragma unroll
  for (int i = 0; i < 8; i++)
    t[ty + i * 8][tx] = W[(size_t)(k0 + ty + i * 8) * 1024 + n0 + tx];
  __syncthreads();
  #pragma unroll
  for (int i = 0; i < 4; i++) {
    const int n = ty + i * 8;
    ushort2 pk;
    pk.x = f2b(t[tx * 2][n]);
    pk.y = f2b(t[tx * 2 + 1][n]);
    *(ushort2*)&Wt[(size_t)(n0 + n) * 1024 + k0 + tx * 2] = pk;
  }
}

// ---------------- fused QKV GEMM 128x128 (m97 structure) ----------------
// Bt = [3072 n][1024 k]; n-range selects dst q/k/vt + bias.
__global__ __launch_bounds__(256) void gemm_qkv(
    const unsigned short* __restrict__ A, const unsigned short* __restrict__ Bt,
    const float* __restrict__ b0, const float* __restrict__ b1, const float* __restrict__ b2,
    unsigned short* __restrict__ dq, unsigned short* __restrict__ dk,
    unsigned short* __restrict__ dv) {
  __shared__ unsigned short As[2][4096];  // [128][32]
  __shared__ unsigned short Bs[2][4096];  // [128][32]
  const int tid = threadIdx.x;
  const int w = tid >> 6, lane = tid & 63;
  const int li = lane & 15, g = lane >> 4;
  const int wm = w >> 1, wn = w & 1;
  const int m0 = blockIdx.x * 128, n0 = blockIdx.y * 128;

  const int seg0 = w * 2, seg1 = w * 2 + 1;
  const int srow0 = seg0 * 16 + (lane >> 2), srow1 = seg1 * 16 + (lane >> 2);
  const int scol = (lane & 3) * 8;
  const unsigned short* gA0 = A + (size_t)(m0 + srow0) * 1024 + scol;
  const unsigned short* gA1 = A + (size_t)(m0 + srow1) * 1024 + scol;
  const unsigned short* gB0 = Bt + (size_t)(n0 + srow0) * 1024 + scol;
  const unsigned short* gB1 = Bt + (size_t)(n0 + srow1) * 1024 + scol;

  f32x4 acc[4][4];
  #pragma unroll
  for (int i = 0; i < 4; i++)
    #pragma unroll
    for (int j = 0; j < 4; j++) acc[i][j] = (f32x4){0.f, 0.f, 0.f, 0.f};

#define GSTAGE(bufi, kt)                                 \
  {                                                      \
    const int ko = (kt) * 32;                            \
    gl_lds16(gA0 + ko, &As[bufi][seg0 * 512]);           \
    gl_lds16(gA1 + ko, &As[bufi][seg1 * 512]);           \
    gl_lds16(gB0 + ko, &Bs[bufi][seg0 * 512]);           \
    gl_lds16(gB1 + ko, &Bs[bufi][seg1 * 512]);           \
  }

  GSTAGE(0, 0)
  int buf = 0;
  for (int kt = 0; kt < 32; kt++) {
    __syncthreads();
    if (kt + 1 < 32) GSTAGE(buf ^ 1, kt + 1)
    bf16x8 af[4], bfr[4];
    #pragma unroll
    for (int mt = 0; mt < 4; mt++)
      af[mt] = *(const bf16x8*)&As[buf][(wm * 64 + mt * 16 + li) * 32 + g * 8];
    #pragma unroll
    for (int nt = 0; nt < 4; nt++)
      bfr[nt] = *(const bf16x8*)&Bs[buf][(wn * 64 + nt * 16 + li) * 32 + g * 8];
    #pragma unroll
    for (int mt = 0; mt < 4; mt++)
      #pragma unroll
      for (int nt = 0; nt < 4; nt++)
        acc[mt][nt] = __builtin_amdgcn_mfma_f32_16x16x32_bf16(af[mt], bfr[nt], acc[mt][nt], 0, 0, 0);
    buf ^= 1;
  }
#undef GSTAGE

  const int sel = n0 >> 10;  // 128-tiles never straddle the 1024 boundaries
  const float* bp = sel == 0 ? b0 : (sel == 1 ? b1 : b2);
  unsigned short* dst = sel == 0 ? dq : (sel == 1 ? dk : dv);
  #pragma unroll
  for (int nt = 0; nt < 4; nt++) {
    const int gc = n0 + wn * 64 + nt * 16 + li;
    const int c = gc & 1023, h = c >> 6, d = c & 63;
    const float bv = bp[c];
    #pragma unroll
    for (int mt = 0; mt < 4; mt++) {
      const int base = m0 + wm * 64 + mt * 16 + g * 4;
      const int bb = base >> 11, s = base & 2047;
      if (sel < 2) {
        #pragma unroll
        for (int r = 0; r < 4; r++)
          dst[((size_t)(bb * 16 + h) * 2048 + s + r) * 64 + d] = f2b_n(acc[mt][nt][r] + bv);
      } else {  // Vt [bh][d][s]: 4 consecutive s -> one 8B store
        ushort4 pk;
        pk.x = f2b_n(acc[mt][nt][0] + bv);
        pk.y = f2b_n(acc[mt][nt][1] + bv);
        pk.z = f2b_n(acc[mt][nt][2] + bv);
        pk.w = f2b_n(acc[mt][nt][3] + bv);
        *(ushort4*)&dst[((size_t)(bb * 16 + h) * 64 + d) * 2048 + s] = pk;
      }
    }
  }
}

// ---------------- out-proj GEMM 128x64 (512 blocks for occupancy) ----------------
__global__ __launch_bounds__(256) void gemm_out(
    const unsigned short* __restrict__ A, const unsigned short* __restrict__ Bt,
    const float* __restrict__ bias, float* __restrict__ dout) {
  __shared__ unsigned short As[2][4096];  // [128][32]
  __shared__ unsigned short Bs[2][2048];  // [64][32]
  const int tid = threadIdx.x;
  const int w = tid >> 6, lane = tid & 63;
  const int li = lane & 15, g = lane >> 4;
  const int m0 = blockIdx.x * 128, n0 = blockIdx.y * 64;

  const int srow0 = w * 32 + (lane >> 2), srow1 = w * 32 + 16 + (lane >> 2);
  const int srowB = w * 16 + (lane >> 2);
  const int scol = (lane & 3) * 8;
  const unsigned short* gA0 = A + (size_t)(m0 + srow0) * 1024 + scol;
  const unsigned short* gA1 = A + (size_t)(m0 + srow1) * 1024 + scol;
  const unsigned short* gB0 = Bt + (size_t)(n0 + srowB) * 1024 + scol;

  f32x4 acc[2][4];
  #pragma unroll
  for (int i = 0; i < 2; i++)
    #pragma unroll
    for (int j = 0; j < 4; j++) acc[i][j] = (f32x4){0.f, 0.f, 0.f, 0.f};

#define OSTAGE(bufi, kt)                                 \
  {                                                      \
    const int ko = (kt) * 32;                            \
    gl_lds16(gA0 + ko, &As[bufi][w * 1024]);             \
    gl_lds16(gA1 + ko, &As[bufi][w * 1024 + 512]);       \
    gl_lds16(gB0 + ko, &Bs[bufi][w * 512]);              \
  }

  OSTAGE(0, 0)
  int buf = 0;
  for (int kt = 0; kt < 32; kt++) {
    __syncthreads();
    if (kt + 1 < 32) OSTAGE(buf ^ 1, kt + 1)
    bf16x8 af[2], bfr[4];
    #pragma unroll
    for (int mt = 0; mt < 2; mt++)
      af[mt] = *(const bf16x8*)&As[buf][(w * 32 + mt * 16 + li) * 32 + g * 8];
    #pragma unroll
    for (int nt = 0; nt < 4; nt++)
      bfr[nt] = *(const bf16x8*)&Bs[buf][(nt * 16 + li) * 32 + g * 8];
    #pragma unroll
    for (int mt = 0; mt < 2; mt++)
      #pragma unroll
      for (int nt = 0; nt < 4; nt++)
        acc[mt][nt] = __builtin_amdgcn_mfma_f32_16x16x32_bf16(af[mt], bfr[nt], acc[mt][nt], 0, 0, 0);
    buf ^= 1;
  }
#undef OSTAGE

  #pragma unroll
  for (int nt = 0; nt < 4; nt++) {
    const int gc = n0 + nt * 16 + li;
    const float bv = bias[gc];
    #pragma unroll
    for (int mt = 0; mt < 2; mt++)
      #pragma unroll
      for (int r = 0; r < 4; r++) {
        const int gr = m0 + w * 32 + mt * 16 + g * 4 + r;
        dout[(size_t)gr * 1024 + gc] = acc[mt][nt][r] + bv;
      }
  }
}

// ---------------- flash attention ----------------
// grid (16, 32) remapped; block 256 (4 waves x 32 q-rows), KVBLK=64.
// Max-free softmax (scores bounded); K/V frag reads amortized over 32 q-rows.
__global__ __launch_bounds__(256, 2) void attn_kernel(
    const unsigned short* __restrict__ qb, const unsigned short* __restrict__ kb,
    const unsigned short* __restrict__ vtb, const int* __restrict__ cause,
    const int* __restrict__ effect, const float* __restrict__ strength,
    unsigned short* __restrict__ attb) {
  __shared__ unsigned short Ks[2][4096];  // [64 key][64 d] swizzled
  __shared__ unsigned short Vs[2][4096];  // [64 d][64 key] swizzled
  __shared__ unsigned short Pl[4][2048];  // per-wave [32 q][64 k] swizzled
  const int tid = threadIdx.x;
  const int w = tid >> 6, lane = tid & 63;
  const int g = lane >> 4, li = lane & 15;
  // XCD-bijective remap: all 16 q-blocks of one bh land on one XCD
  const int lid = blockIdx.y * 16 + blockIdx.x;       // [0,512)
  const int bh = ((lid & 7) << 2) | ((lid >> 3) & 3);
  const int qblk = lid >> 5;                          // [0,16)
  const int b = bh >> 4, h = bh & 15;
  const int q0 = qblk * 128 + w * 32;

  const unsigned short* kbp = kb + (size_t)bh * 2048 * 64;
  const unsigned short* vbp = vtb + (size_t)bh * 64 * 2048;

  bf16x8 qa[2][2];
  #pragma unroll
  for (int i = 0; i < 2; i++) {
    const unsigned short* qrow = qb + ((size_t)bh * 2048 + q0 + i * 16 + li) * 64 + g * 8;
    qa[i][0] = *(const bf16x8*)(qrow);
    qa[i][1] = *(const bf16x8*)(qrow + 32);
  }

  const float LOG2E = 1.44269504f;
  const float fmask = 1.0f - 0.5f * strength[0];
  const float c0s2 = 0.125f * LOG2E;
  const float c1s2 = c0s2 * fmask;
  float mrr[2][4];
  #pragma unroll
  for (int i = 0; i < 2; i++)
    #pragma unroll
    for (int r = 0; r < 4; r++)
      mrr[i][r] = cause[b * 2048 + q0 + i * 16 + g * 4 + r] ? c1s2 : c0s2;
  const int* eff = effect + b * 2048;

  // staging geometry: 8 segments of 1KB (8 rows x 128B); source col pre-XORed
  const int seg0 = w * 2, seg1 = w * 2 + 1;
  const int r0 = seg0 * 8 + (lane >> 3), r1 = seg1 * 8 + (lane >> 3);
  const int cs = (((lane & 7) ^ (lane >> 3)) * 8);  // shorts
  const unsigned short* kg0 = kbp + (size_t)r0 * 64 + cs;
  const unsigned short* kg1 = kbp + (size_t)r1 * 64 + cs;
  const unsigned short* vg0 = vbp + (size_t)r0 * 2048 + cs;
  const unsigned short* vg1 = vbp + (size_t)r1 * 2048 + cs;

#define ASTAGE(bufi, t)                                        \
  {                                                            \
    gl_lds16(kg0 + (size_t)(t) * 4096, &Ks[bufi][seg0 * 512]); \
    gl_lds16(kg1 + (size_t)(t) * 4096, &Ks[bufi][seg1 * 512]); \
    gl_lds16(vg0 + (t) * 64, &Vs[bufi][seg0 * 512]);           \
    gl_lds16(vg1 + (t) * 64, &Vs[bufi][seg1 * 512]);           \
  }

  // swizzled frag-read columns (shorts): row&7 == li&7 for all frag reads
  const int swz = (li & 7) << 4;  // bytes
  const int col0 = ((g * 16) ^ swz) >> 1;
  const int col1 = ((64 + g * 16) ^ swz) >> 1;

  float l[2][4];
  f32x4 acc[2][4];
  #pragma unroll
  for (int i = 0; i < 2; i++) {
    #pragma unroll
    for (int r = 0; r < 4; r++) l[i][r] = 0.f;
    #pragma unroll
    for (int c = 0; c < 4; c++) acc[i][c] = (f32x4){0.f, 0.f, 0.f, 0.f};
  }

  ASTAGE(0, 0)
  int buf = 0;
  for (int t = 0; t < 32; t++) {
    __syncthreads();
    if (t + 1 < 32) ASTAGE(buf ^ 1, t + 1)
    const int kk = t * 64;
    #pragma unroll
    for (int s = 0; s < 4; s++) {
      const bf16x8 kf0 = *(const bf16x8*)&Ks[buf][s * 1024 + li * 64 + col0];
      const bf16x8 kf1 = *(const bf16x8*)&Ks[buf][s * 1024 + li * 64 + col1];
      const bool eb = eff[kk + s * 16 + li] != 0;
      #pragma unroll
      for (int i = 0; i < 2; i++) {
        f32x4 z = (f32x4){0.f, 0.f, 0.f, 0.f};
        z = __builtin_amdgcn_mfma_f32_16x16x32_bf16(qa[i][0], kf0, z, 0, 0, 0);
        z = __builtin_amdgcn_mfma_f32_16x16x32_bf16(qa[i][1], kf1, z, 0, 0, 0);
        #pragma unroll
        for (int r = 0; r < 4; r++) {
          const float p = fexp2(z[r] * (eb ? mrr[i][r] : c0s2));
          l[i][r] += p;
          const int row = i * 16 + g * 4 + r;
          Pl[w][row * 64 + (((s * 32 + li * 2) ^ ((row & 7) << 4)) >> 1)] = f2b_n(p);
        }
      }
    }
    bf16x8 pa[2][2];
    #pragma unroll
    for (int i = 0; i < 2; i++) {
      pa[i][0] = *(const bf16x8*)&Pl[w][(i * 16 + li) * 64 + col0];
      pa[i][1] = *(const bf16x8*)&Pl[w][(i * 16 + li) * 64 + col1];
    }
    #pragma unroll
    for (int c = 0; c < 4; c++) {
      const bf16x8 vf0 = *(const bf16x8*)&Vs[buf][c * 1024 + li * 64 + col0];
      const bf16x8 vf1 = *(const bf16x8*)&Vs[buf][c * 1024 + li * 64 + col1];
      #pragma unroll
      for (int i = 0; i < 2; i++) {
        acc[i][c] = __builtin_amdgcn_mfma_f32_16x16x32_bf16(pa[i][0], vf0, acc[i][c], 0, 0, 0);
        acc[i][c] = __builtin_amdgcn_mfma_f32_16x16x32_bf16(pa[i][1], vf1, acc[i][c], 0, 0, 0);
      }
    }
    buf ^= 1;
  }
#undef ASTAGE

  // single final l-reduce across the 16 lanes of each group
  #pragma unroll
  for (int off = 1; off < 16; off <<= 1)
    #pragma unroll
    for (int i = 0; i < 2; i++)
      #pragma unroll
      for (int r = 0; r < 4; r++) l[i][r] += __shfl_xor(l[i][r], off, 16);
  #pragma unroll
  for (int i = 0; i < 2; i++)
    #pragma unroll
    for (int r = 0; r < 4; r++) l[i][r] = 1.0f / l[i][r];
  #pragma unroll
  for (int i = 0; i < 2; i++)
    #pragma unroll
    for (int c = 0; c < 4; c++)
      #pragma unroll
      for (int r = 0; r < 4; r++) {
        const int row = q0 + i * 16 + g * 4 + r;
        attb[(size_t)(b * 2048 + row) * 1024 + h * 64 + c * 16 + li] = f2b_n(acc[i][c][r] * l[i][r]);
      }
}

// ---------------- launch ----------------

extern "C" void kernel_launch(void* const* d_in, const int* in_sizes, int n_in,
                              void* d_out, int out_size, void* d_ws, size_t ws_size,
                              hipStream_t stream) {
  (void)in_sizes; (void)n_in; (void)out_size; (void)ws_size;
  const float* x = (const float*)d_in[0];
  const int* cause = (const int*)d_in[1];
  const int* effect = (const int*)d_in[2];
  const float* strength = (const float*)d_in[3];
  const float* Wq = (const float*)d_in[4];
  const float* bq = (const float*)d_in[5];
  const float* Wk = (const float*)d_in[6];
  const float* bk = (const float*)d_in[7];
  const float* Wv = (const float*)d_in[8];
  const float* bv = (const float*)d_in[9];
  const float* Wo = (const float*)d_in[10];
  const float* bo = (const float*)d_in[11];
  float* out = (float*)d_out;

  char* ws = (char*)d_ws;
  unsigned short* xb  = (unsigned short*)(ws);                // 8 MB
  unsigned short* wqt = (unsigned short*)(ws + (8u << 20));   // 2 MB each, q|k|v|o contiguous
  unsigned short* qbf = (unsigned short*)(ws + (16u << 20));  // 8 MB
  unsigned short* kbf = (unsigned short*)(ws + (24u << 20));  // 8 MB
  unsigned short* vtb = (unsigned short*)(ws + (32u << 20));  // 8 MB
  unsigned short* wot = wqt + 3u * 1048576u;
  unsigned short* attb = xb;  // reuse after projections

  cvt_x_kernel<<<4096, 256, 0, stream>>>(x, xb, 1048576);
  cvt_w4_kernel<<<dim3(16, 32, 4), dim3(32, 8), 0, stream>>>(Wq, Wk, Wv, Wo, wqt);

  gemm_qkv<<<dim3(32, 24), 256, 0, stream>>>(xb, wqt, bq, bk, bv, qbf, kbf, vtb);
  attn_kernel<<<dim3(16, 32), 256, 0, stream>>>(qbf, kbf, vtb, cause, effect, strength, attb);
  gemm_out<<<dim3(32, 16), 256, 0, stream>>>(attb, wot, bo, out);
}